// Round 3
// baseline (134.530 us; speedup 1.0000x reference)
//
#include <hip/hip_runtime.h>
#include <hip/hip_bf16.h>

// Conv2dWithLoRA: out = conv3x3(x, W_eff) + b, where W_eff = W + 2.0 * B@A.
// LoRA folded into weights -> single implicit-GEMM conv, bf16 MFMA, fp32 accum.
// M = 16*64*64 = 65536 pixels, N = 256 outs, K = 128*9 = 1152.
// R1: BK=64 + XOR-swizzled LDS, halo fused in pad.  R2: LDS stride fix.
// R3: 256x256 tile, 8 waves, depth-1 double buffer -> 859 TF, MfmaUtil 32%.
// R4: BK=32 QUAD-buffer, depth-3 pipeline (T3+T4):
//   - 36 chunks of K=32; 4 LDS buffers of 32 KB (same 128 KiB total).
//   - iter t: vmcnt(8) [chunks t+1,t+2 stay IN FLIGHT - never drain to 0],
//     one s_barrier, stage chunk t+3 (4 VMEM instrs/wave), 12 ds_read_b128,
//     32 MFMA. Prefetch cover = 3 iters (~1500 cyc) >> HBM latency.
//   - one barrier per chunk (was 2): stage(t+3) targets buf (t-1)&3 whose
//     reads finished before the preceding barrier (ds_read->MFMA data dep).
//   - swizzle: rows are 32 elems (4x 16B chunks); physical chunk of logical
//     (row,q) = q^(row&3); inverse pre-applied on per-lane GLOBAL address,
//     LDS dest stays linear (global_load_lds requirement).
// R5: resubmit of R4 verbatim — previous round died to a container/infra
//     failure with no counters; design audit found no deadlock/race path.

#define CIN   128
#define COUT  256
#define NBAT  16
#define HPAD  66
#define WPAD  66

typedef __bf16 bf16x8 __attribute__((ext_vector_type(8)));
typedef float f32x4 __attribute__((ext_vector_type(4)));

#define XPAD_ELEMS ((size_t)NBAT * HPAD * WPAD * CIN)   // 8,921,088
#define XPAD_BYTES (XPAD_ELEMS * 2)                      // 17,842,176
#define WT_ELEMS   ((size_t)9 * COUT * CIN)              // 294,912
#define WS_NEED    (XPAD_BYTES + WT_ELEMS * 2)

typedef __attribute__((address_space(1))) void gvoid;
typedef __attribute__((address_space(3))) void lvoid;

__device__ __forceinline__ void load_lds16(const void* g, void* l) {
    // async global->LDS, 16B per lane; LDS dest = wave-uniform base + lane*16
    __builtin_amdgcn_global_load_lds((gvoid*)g, (lvoid*)l, 16, 0, 0);
}

// ---------------------------------------------------------------------------
// Fused pre-kernel: blocks [0,1024) = pad_x, blocks [1024,1152) = prep_w.
__global__ void pad_prep(const float* __restrict__ x, __bf16* __restrict__ xpad,
                         const float* __restrict__ W, const float* __restrict__ lA,
                         const float* __restrict__ lB, __hip_bfloat16* __restrict__ Wt) {
    __shared__ float tile[128][66];
    const int t = threadIdx.x;

    if (blockIdx.x >= 1024) {
        // ---- prep_w: 128 blocks, each thread owns one (o,c), loops 9 taps
        const int idx = (blockIdx.x - 1024) * 256 + t;   // o*128 + c
        const int c = idx & 127;
        const int o = idx >> 7;
        float lb[8];
#pragma unroll
        for (int r = 0; r < 8; ++r) lb[r] = lB[o * 8 + r];
#pragma unroll
        for (int tap = 0; tap < 9; ++tap) {
            float acc = W[(o * 128 + c) * 9 + tap];
            float s = 0.f;
#pragma unroll
            for (int r = 0; r < 8; ++r)
                s += lb[r] * lA[r * 1152 + c * 9 + tap];
            Wt[tap * 32768 + idx] = __float2bfloat16(acc + 2.0f * s);
        }
        return;
    }

    // ---- pad_x: NCHW fp32 -> NHWC bf16 with +1 zero halo
    const int n = blockIdx.x >> 6;
    const int h = blockIdx.x & 63;
    const float* src = x + (size_t)n * 128 * 4096 + (size_t)h * 64;
#pragma unroll
    for (int i = 0; i < 8; ++i) {                      // 2048 float4 total
        int g  = i * 256 + t;
        int c  = g >> 4;
        int w4 = (g & 15) * 4;
        const float4 v = *reinterpret_cast<const float4*>(src + (size_t)c * 4096 + w4);
        const int wb = w4 ^ (((c >> 3) & 7) << 2);     // swizzle (bits 2..4)
        tile[c][wb + 0] = v.x; tile[c][wb + 1] = v.y;
        tile[c][wb + 2] = v.z; tile[c][wb + 3] = v.w;
    }
    __syncthreads();
    __bf16* dst = xpad + ((size_t)(n * 66 + h + 1) * 66 + 1) * 128;
#pragma unroll
    for (int i = 0; i < 4; ++i) {                      // 64w x 128c bf16 = 16KB
        int g  = i * 256 + t;
        int w  = g >> 4;
        int c0 = (g & 15) * 8;
        const int swr = ((c0 >> 3) & 7) << 2;          // (c0+j)>>3 == c0>>3, j<8
        bf16x8 v;
#pragma unroll
        for (int j = 0; j < 8; ++j) v[j] = (__bf16)tile[c0 + j][w ^ swr];
        *reinterpret_cast<bf16x8*>(dst + (size_t)w * 128 + c0) = v;
    }
    // halo: left/right pixel of this padded row
    bf16x8 z = {};
    __bf16* rowbase = xpad + (size_t)(n * 66 + h + 1) * 66 * 128;
    if (t < 32) {
        int ww = (t < 16) ? 0 : 65;
        int c0 = (t & 15) * 8;
        *reinterpret_cast<bf16x8*>(rowbase + (size_t)ww * 128 + c0) = z;
    }
    // top/bottom halo rows (full 66 px)
    if (h == 0 || h == 63) {
        __bf16* hrow = xpad + (size_t)(n * 66 + (h == 0 ? 0 : 65)) * 66 * 128;
        for (int i = t; i < 66 * 16; i += 256)
            *reinterpret_cast<bf16x8*>(hrow + (size_t)i * 8) = z;
    }
}

// ---------------------------------------------------------------------------
// Main kernel: implicit-GEMM conv. Tile 256(o) x 256(pix), BK=32, 8 waves,
// quad-buffered depth-3 pipeline.
//
// LDS map (bf16 elems): A bufs 0..3 at [0 + q*8192), B bufs at [32768 + q*8192)
// where q = chunk&3. Chunk u (0..35): tap = u>>2, cb = u&3 (32-ch slice).
//
// Per iteration t: vmcnt(8) -> chunk t's 4 stage instrs complete, chunks
// t+1/t+2 (8 instrs) remain in flight; s_barrier (all waves' stages landed);
// issue stage(t+3); 12 ds_read_b128; 32 MFMA. Tail peels t=33,34,35 with
// vmcnt(8)/(4)/(0).
__global__ void __launch_bounds__(512, 2) conv_mfma(
    const __bf16* __restrict__ xpad, const __bf16* __restrict__ Wt,
    const float* __restrict__ bias, float* __restrict__ out) {
    __shared__ __align__(16) __bf16 lds[65536];        // 128 KiB

    const int tid  = threadIdx.x;
    const int wv   = tid >> 6;                         // 0..7
    const int lane = tid & 63;

    const int n  = blockIdx.x >> 4;                    // 16 tiles per image
    const int h0 = (blockIdx.x & 15) << 2;             // 4 output rows per tile

    // ---- staging addresses --------------------------------------------------
    // One stage instr covers 16 rows x 32 elems (64 lanes x 16B = 1 KB).
    // lane l: row = base + (l>>2), physical chunk slot = l&3 must receive
    // logical chunk (l&3) ^ (row&3)  (row bases are multiples of 16).
    const int lrow = lane >> 2;                                    // 0..15
    const int lswz = (((lane & 3) ^ (lrow & 3)) << 3);             // elems
    const __bf16* aG[2];
    const __bf16* bG[2];
#pragma unroll
    for (int j = 0; j < 2; ++j) {
        const int r0 = j * 128 + wv * 16;              // first row of this instr
        aG[j] = Wt + (r0 + lrow) * 128 + lswz;
        // pixel p = r0 + lrow; within one instr p>>6 is constant (r0 mult of 16)
        bG[j] = xpad + (((size_t)(n * 66 + h0 + (r0 >> 6)) * 66 + (r0 & 63) + lrow) * 128) + lswz;
    }

    // ---- fragment-read addresses -------------------------------------------
    const int wo   = (wv >> 2) << 7;                   // o offset: 0 / 128
    const int wpix = (wv & 3) << 6;                    // pix offset: 0/64/128/192
    const int fr   = lane & 15;
    // logical k-chunk = lane>>4 (8 elems each, K=32); physical = logical^(row&3)
    const int fphys = (((lane >> 4) ^ (lane & 3)) << 3);
    const int a_rd = (wo + fr) * 32 + fphys;           // + mi*512 + buf
    const int b_rd = (wpix + fr) * 32 + fphys;         // + ni*512 + buf

    f32x4 acc[8][4] = {};

#define STAGE(u) do {                                                          \
        const int tap_ = (u) >> 2, cb_ = (u) & 3;                              \
        const int kh_ = (tap_ >= 6) ? 2 : (tap_ >= 3 ? 1 : 0);                 \
        const int kw_ = tap_ - kh_ * 3;                                        \
        const int ao_ = tap_ * 32768 + cb_ * 32;                               \
        const int bo_ = (kh_ * 66 + kw_) * 128 + cb_ * 32;                     \
        const int lb_ = ((u) & 3) * 8192;                                      \
        load_lds16(aG[0] + ao_, lds + lb_ + (wv * 16) * 32);                   \
        load_lds16(aG[1] + ao_, lds + lb_ + (128 + wv * 16) * 32);             \
        load_lds16(bG[0] + bo_, lds + 32768 + lb_ + (wv * 16) * 32);           \
        load_lds16(bG[1] + bo_, lds + 32768 + lb_ + (128 + wv * 16) * 32);     \
    } while (0)

#define COMPUTE(t) do {                                                        \
        const int lb_ = ((t) & 3) * 8192;                                      \
        const __bf16* Ab = lds + lb_ + a_rd;                                   \
        const __bf16* Bb = lds + 32768 + lb_ + b_rd;                           \
        bf16x8 af[8], bfr[4];                                                  \
        _Pragma("unroll")                                                      \
        for (int ni = 0; ni < 4; ++ni)                                         \
            bfr[ni] = *reinterpret_cast<const bf16x8*>(Bb + ni * 512);         \
        _Pragma("unroll")                                                      \
        for (int mi = 0; mi < 8; ++mi)                                         \
            af[mi] = *reinterpret_cast<const bf16x8*>(Ab + mi * 512);          \
        __builtin_amdgcn_s_setprio(1);                                         \
        _Pragma("unroll")                                                      \
        for (int mi = 0; mi < 8; ++mi)                                         \
            _Pragma("unroll")                                                  \
            for (int ni = 0; ni < 4; ++ni)                                     \
                acc[mi][ni] = __builtin_amdgcn_mfma_f32_16x16x32_bf16(         \
                    af[mi], bfr[ni], acc[mi][ni], 0, 0, 0);                    \
        __builtin_amdgcn_s_setprio(0);                                         \
    } while (0)

    // prologue: prefetch chunks 0,1,2 (12 VMEM instrs in flight)
    STAGE(0); STAGE(1); STAGE(2);

    for (int t = 0; t < 33; ++t) {
        // chunk t's 4 loads done; t+1,t+2 (8 instrs) stay in flight
        asm volatile("s_waitcnt vmcnt(8)" ::: "memory");
        __builtin_amdgcn_sched_barrier(0);
        __builtin_amdgcn_s_barrier();                  // all waves' stages landed
        __builtin_amdgcn_sched_barrier(0);
        STAGE(t + 3);
        COMPUTE(t);
    }
    // t = 33: outstanding = chunks 33,34,35 (12 instrs)
    asm volatile("s_waitcnt vmcnt(8)" ::: "memory");
    __builtin_amdgcn_sched_barrier(0);
    __builtin_amdgcn_s_barrier();
    COMPUTE(33);
    // t = 34: outstanding = chunks 34,35 (8 instrs)
    asm volatile("s_waitcnt vmcnt(4)" ::: "memory");
    __builtin_amdgcn_sched_barrier(0);
    __builtin_amdgcn_s_barrier();
    COMPUTE(34);
    // t = 35: outstanding = chunk 35 (4 instrs)
    asm volatile("s_waitcnt vmcnt(0)" ::: "memory");
    __builtin_amdgcn_sched_barrier(0);
    __builtin_amdgcn_s_barrier();
    COMPUTE(35);

#undef STAGE
#undef COMPUTE

    // epilogue: D row=(lane>>4)*4+j (o), col=lane&15 (pix); + bias
    const int col  = lane & 15;
    const int orow = (lane >> 4) << 2;
    const int h    = h0 + (wpix >> 6);
#pragma unroll
    for (int mi = 0; mi < 8; ++mi) {
        const int obm = wo + mi * 16 + orow;
#pragma unroll
        for (int j = 0; j < 4; ++j) {
            const int o = obm + j;
            const float bj = bias[o];
            float* orow_ptr = out + (((size_t)n * 256 + o) * 64 + h) * 64;
#pragma unroll
            for (int ni = 0; ni < 4; ++ni)
                orow_ptr[ni * 16 + col] = acc[mi][ni][j] + bj;
        }
    }
}

// ---------------------------------------------------------------------------
// Fallback (only if workspace too small): naive fp32, correct but slow.
__global__ void conv_naive(const float* __restrict__ x, const float* __restrict__ W,
                           const float* __restrict__ b, const float* __restrict__ lA,
                           const float* __restrict__ lB, float* __restrict__ out) {
    int idx = blockIdx.x * 256 + threadIdx.x;          // ((n*256+o)*64+h)*64+w
    int w = idx & 63, h = (idx >> 6) & 63, o = (idx >> 12) & 255, n = idx >> 20;
    float acc = b[o];
    float hr[8] = {0, 0, 0, 0, 0, 0, 0, 0};
    for (int c = 0; c < 128; ++c)
        for (int kh = 0; kh < 3; ++kh) {
            int hy = h + kh - 1;
            if (hy < 0 || hy > 63) continue;
            for (int kw = 0; kw < 3; ++kw) {
                int wx = w + kw - 1;
                if (wx < 0 || wx > 63) continue;
                float xv = x[((n * 128 + c) * 64 + hy) * 64 + wx];
                int ka = c * 9 + kh * 3 + kw;
                acc += W[(o * 128 + c) * 9 + kh * 3 + kw] * xv;
#pragma unroll
                for (int r = 0; r < 8; ++r) hr[r] += lA[r * 1152 + ka] * xv;
            }
        }
    float ls = 0.f;
#pragma unroll
    for (int r = 0; r < 8; ++r) ls += lB[o * 8 + r] * hr[r];
    out[idx] = acc + 2.0f * ls;
}

// ---------------------------------------------------------------------------
extern "C" void kernel_launch(void* const* d_in, const int* in_sizes, int n_in,
                              void* d_out, int out_size, void* d_ws, size_t ws_size,
                              hipStream_t stream) {
    const float* x  = (const float*)d_in[0];
    const float* W  = (const float*)d_in[1];
    const float* b  = (const float*)d_in[2];
    const float* lA = (const float*)d_in[3];
    const float* lB = (const float*)d_in[4];
    float* out = (float*)d_out;

    if (ws_size < WS_NEED) {
        conv_naive<<<out_size / 256, 256, 0, stream>>>(x, W, b, lA, lB, out);
        return;
    }

    __bf16* xpad = (__bf16*)d_ws;
    __hip_bfloat16* Wt = (__hip_bfloat16*)((char*)d_ws + XPAD_BYTES);

    pad_prep<<<1024 + 128, 256, 0, stream>>>(x, xpad, W, lA, lB, Wt);
    conv_mfma<<<256, 512, 0, stream>>>(xpad, (const __bf16*)Wt, b, out);
}